// Round 1
// baseline (5465.819 us; speedup 1.0000x reference)
//
#include <hip/hip_runtime.h>
#include <hip/hip_bf16.h>

#define CIN  128
#define COUT 128
#define BN_EPS 1e-5f

// ---------------------------------------------------------------------------
// Kernel 1: Z_theta[N,128] = Z_H[N,128] @ W[128,128] + b
// W staged in LDS (64 KB), 32-row Z tiles staged in LDS (16 KB).
// Each thread computes a 4-row x 4-col block (float4 cols).
// ---------------------------------------------------------------------------
__global__ __launch_bounds__(256) void gemm_kernel(
    const float* __restrict__ Z, const float* __restrict__ W,
    const float* __restrict__ b, float* __restrict__ Zt, int N)
{
    __shared__ float Wlds[CIN * COUT];      // 64 KB
    __shared__ float zl[32][CIN];           // 16 KB

    const int t = threadIdx.x;

    // stage W once per block: 4096 float4, 16 per thread
    for (int i = t; i < (CIN * COUT) / 4; i += 256) {
        ((float4*)Wlds)[i] = ((const float4*)W)[i];
    }

    const int c4 = (t & 31) * 4;   // column group [c4, c4+4)
    const int rg = t >> 5;         // row group 0..7 -> rows rg*4 .. rg*4+3
    const float4 bias = *((const float4*)(b + c4));

    const int ntiles = (N + 31) / 32;
    for (int tile = blockIdx.x; tile < ntiles; tile += gridDim.x) {
        const int row0 = tile * 32;
        __syncthreads();   // previous-iter zl readers done (also covers W 1st iter)
        // stage 32 rows of Z: 1024 float4, 4 per thread
        for (int i = t; i < 1024; i += 256) {
            const int r  = i >> 5;
            const int cc = i & 31;
            const int gr = row0 + r;
            float4 v = make_float4(0.f, 0.f, 0.f, 0.f);
            if (gr < N) v = ((const float4*)(Z + (size_t)gr * CIN))[cc];
            ((float4*)&zl[r][0])[cc] = v;
        }
        __syncthreads();

        float4 acc[4];
#pragma unroll
        for (int r = 0; r < 4; ++r) acc[r] = bias;

        for (int k = 0; k < CIN; ++k) {
            const float4 w = *((const float4*)&Wlds[k * COUT + c4]);
#pragma unroll
            for (int r = 0; r < 4; ++r) {
                const float z = zl[rg * 4 + r][k];
                acc[r].x += z * w.x;
                acc[r].y += z * w.y;
                acc[r].z += z * w.z;
                acc[r].w += z * w.w;
            }
        }

#pragma unroll
        for (int r = 0; r < 4; ++r) {
            const int gr = row0 + rg * 4 + r;
            if (gr < N) *((float4*)(Zt + (size_t)gr * COUT + c4)) = acc[r];
        }
    }
}

// ---------------------------------------------------------------------------
// Kernel 2: COO SpMM scatter with atomics.
// 32 threads per edge, float4 per thread (4 atomicAdds).
// ---------------------------------------------------------------------------
__global__ __launch_bounds__(256) void spmm_atomic(
    const float* __restrict__ Zt, const float* __restrict__ vals,
    const int* __restrict__ rows, const int* __restrict__ cols,
    float* __restrict__ Zc, int nnz)
{
    const long gid = (long)blockIdx.x * 256 + threadIdx.x;
    const long e = gid >> 5;
    if (e >= nnz) return;
    const int j4 = (int)(gid & 31) * 4;

    const int   r = rows[e];
    const int   c = cols[e];
    const float v = vals[e];

    const float4 g = *((const float4*)(Zt + (size_t)c * COUT + j4));
    float* dst = Zc + (size_t)r * COUT + j4;
    atomicAdd(dst + 0, v * g.x);
    atomicAdd(dst + 1, v * g.y);
    atomicAdd(dst + 2, v * g.z);
    atomicAdd(dst + 3, v * g.w);
}

// ---------------------------------------------------------------------------
// Kernel 3: per-channel sum / sumsq partial reduction -> stats[256]
// stats[0..127] = sum, stats[128..255] = sumsq  (must be pre-zeroed)
// ---------------------------------------------------------------------------
__global__ __launch_bounds__(256) void stats_partial(
    const float* __restrict__ Zc, float* __restrict__ stats, int N)
{
    const int ch   = threadIdx.x & 127;
    const int half = threadIdx.x >> 7;   // 0 or 1

    float s = 0.f, ss = 0.f;
    for (int r = blockIdx.x * 2 + half; r < N; r += gridDim.x * 2) {
        const float x = Zc[(size_t)r * COUT + ch];
        s  += x;
        ss += x * x;
    }

    __shared__ float buf[256];
    buf[threadIdx.x] = s;
    __syncthreads();
    if (half == 0) s += buf[128 + ch];
    __syncthreads();
    buf[threadIdx.x] = ss;
    __syncthreads();
    if (half == 0) {
        ss += buf[128 + ch];
        atomicAdd(&stats[ch], s);
        atomicAdd(&stats[128 + ch], ss);
    }
}

// ---------------------------------------------------------------------------
// Kernel 4: BN(normalize) + ReLU + row-max -> out[N]
// One 64-lane wave per row, 2 channels per lane.
// ---------------------------------------------------------------------------
__global__ __launch_bounds__(256) void finalize_kernel(
    const float* __restrict__ Zc, const float* __restrict__ stats,
    const float* __restrict__ gamma, const float* __restrict__ beta,
    float* __restrict__ out, int N)
{
    const int row = blockIdx.x * 4 + (threadIdx.x >> 6);
    if (row >= N) return;
    const int lane = threadIdx.x & 63;
    const int c0 = lane * 2;

    const float2 x = *((const float2*)(Zc + (size_t)row * COUT + c0));

    const float invN = 1.0f / (float)N;
    const float m0 = stats[c0] * invN;
    const float m1 = stats[c0 + 1] * invN;
    const float v0 = stats[128 + c0] * invN - m0 * m0;
    const float v1 = stats[128 + c0 + 1] * invN - m1 * m1;
    const float sc0 = gamma[c0]     * rsqrtf(v0 + BN_EPS);
    const float sc1 = gamma[c0 + 1] * rsqrtf(v1 + BN_EPS);

    float y0 = (x.x - m0) * sc0 + beta[c0];
    float y1 = (x.y - m1) * sc1 + beta[c0 + 1];
    y0 = fmaxf(y0, 0.f);
    y1 = fmaxf(y1, 0.f);

    float mx = fmaxf(y0, y1);
#pragma unroll
    for (int off = 32; off > 0; off >>= 1)
        mx = fmaxf(mx, __shfl_xor(mx, off));

    if (lane == 0) out[row] = mx;
}

// ---------------------------------------------------------------------------
extern "C" void kernel_launch(void* const* d_in, const int* in_sizes, int n_in,
                              void* d_out, int out_size, void* d_ws, size_t ws_size,
                              hipStream_t stream)
{
    const float* Z_H   = (const float*)d_in[0];
    const float* vals  = (const float*)d_in[1];
    const float* W     = (const float*)d_in[2];
    const float* b     = (const float*)d_in[3];
    const float* gamma = (const float*)d_in[4];
    const float* beta  = (const float*)d_in[5];
    const int*   rows  = (const int*)d_in[6];
    const int*   cols  = (const int*)d_in[7];
    float* out = (float*)d_out;

    const int N   = in_sizes[0] / CIN;
    const int nnz = in_sizes[1];

    // workspace layout
    char* ws = (char*)d_ws;
    float* Zt    = (float*)ws;                                   // N*128 f32
    float* Zc    = (float*)(ws + (size_t)N * COUT * sizeof(float));
    float* stats = (float*)(ws + 2 * (size_t)N * COUT * sizeof(float));

    // zero Z_conv and stats (on-stream, graph-capturable)
    hipMemsetAsync(Zc, 0, (size_t)N * COUT * sizeof(float), stream);
    hipMemsetAsync(stats, 0, 256 * sizeof(float), stream);

    // 1) GEMM
    gemm_kernel<<<512, 256, 0, stream>>>(Z_H, W, b, Zt, N);

    // 2) SpMM scatter (8 edges per 256-thread block)
    {
        const int blocks = (nnz + 7) / 8;
        spmm_atomic<<<blocks, 256, 0, stream>>>(Zt, vals, rows, cols, Zc, nnz);
    }

    // 3) per-channel stats
    stats_partial<<<1024, 256, 0, stream>>>(Zc, stats, N);

    // 4) BN + ReLU + rowmax
    {
        const int blocks = (N + 3) / 4;
        finalize_kernel<<<blocks, 256, 0, stream>>>(Zc, stats, gamma, beta, out, N);
    }
}

// Round 2
// 1016.027 us; speedup vs baseline: 5.3796x; 5.3796x over previous
//
#include <hip/hip_runtime.h>
#include <hip/hip_bf16.h>

#define CIN  128
#define COUT 128
#define BN_EPS 1e-5f

// ---------------------------------------------------------------------------
// Kernel 1: Z_theta[N,128] = Z_H[N,128] @ W[128,128] + b
// W staged in LDS (64 KB), 32-row Z tiles staged in LDS (16 KB).
// ---------------------------------------------------------------------------
__global__ __launch_bounds__(256) void gemm_kernel(
    const float* __restrict__ Z, const float* __restrict__ W,
    const float* __restrict__ b, float* __restrict__ Zt, int N)
{
    __shared__ float Wlds[CIN * COUT];      // 64 KB
    __shared__ float zl[32][CIN];           // 16 KB

    const int t = threadIdx.x;

    for (int i = t; i < (CIN * COUT) / 4; i += 256) {
        ((float4*)Wlds)[i] = ((const float4*)W)[i];
    }

    const int c4 = (t & 31) * 4;
    const int rg = t >> 5;
    const float4 bias = *((const float4*)(b + c4));

    const int ntiles = (N + 31) / 32;
    for (int tile = blockIdx.x; tile < ntiles; tile += gridDim.x) {
        const int row0 = tile * 32;
        __syncthreads();
        for (int i = t; i < 1024; i += 256) {
            const int r  = i >> 5;
            const int cc = i & 31;
            const int gr = row0 + r;
            float4 v = make_float4(0.f, 0.f, 0.f, 0.f);
            if (gr < N) v = ((const float4*)(Z + (size_t)gr * CIN))[cc];
            ((float4*)&zl[r][0])[cc] = v;
        }
        __syncthreads();

        float4 acc[4];
#pragma unroll
        for (int r = 0; r < 4; ++r) acc[r] = bias;

        for (int k = 0; k < CIN; ++k) {
            const float4 w = *((const float4*)&Wlds[k * COUT + c4]);
#pragma unroll
            for (int r = 0; r < 4; ++r) {
                const float z = zl[rg * 4 + r][k];
                acc[r].x += z * w.x;
                acc[r].y += z * w.y;
                acc[r].z += z * w.z;
                acc[r].w += z * w.w;
            }
        }

#pragma unroll
        for (int r = 0; r < 4; ++r) {
            const int gr = row0 + rg * 4 + r;
            if (gr < N) *((float4*)(Zt + (size_t)gr * COUT + c4)) = acc[r];
        }
    }
}

// ---------------------------------------------------------------------------
// Kernel 2a: histogram of row ids (int atomics, low contention)
// ---------------------------------------------------------------------------
__global__ __launch_bounds__(256) void hist_kernel(
    const int* __restrict__ rows, int* __restrict__ cnt, int nnz)
{
    for (int i = blockIdx.x * 256 + threadIdx.x; i < nnz; i += gridDim.x * 256)
        atomicAdd(&cnt[rows[i]], 1);
}

// ---------------------------------------------------------------------------
// Kernel 2b: single-block exclusive scan of row counts -> rowptr[N+1], rowcur[N]
// 1024 threads; each thread serially scans a contiguous chunk (~98 rows).
// ---------------------------------------------------------------------------
__global__ __launch_bounds__(1024) void scan_kernel(
    const int* __restrict__ cnt, int* __restrict__ rowptr,
    int* __restrict__ rowcur, int N)
{
    const int t = threadIdx.x;
    const int chunk = (N + 1023) / 1024;
    const int begin = t * chunk;
    const int end   = min(begin + chunk, N);

    int s = 0;
    for (int i = begin; i < end; ++i) s += cnt[i];

    __shared__ int sums[1024];
    sums[t] = s;
    __syncthreads();

    // Hillis-Steele inclusive scan
    for (int off = 1; off < 1024; off <<= 1) {
        int v = (t >= off) ? sums[t - off] : 0;
        __syncthreads();
        sums[t] += v;
        __syncthreads();
    }

    int run = (t == 0) ? 0 : sums[t - 1];   // exclusive prefix
    for (int i = begin; i < end; ++i) {
        rowptr[i] = run;
        rowcur[i] = run;
        run += cnt[i];
    }
    if (t == 0) rowptr[N] = sums[1023];
}

// ---------------------------------------------------------------------------
// Kernel 2c: counting-sort scatter of edges into CSR buckets.
// Packs (col, val) into 8 bytes, written exactly once per edge.
// ---------------------------------------------------------------------------
__global__ __launch_bounds__(256) void scatter_kernel(
    const int* __restrict__ rows, const int* __restrict__ cols,
    const float* __restrict__ vals, int* __restrict__ rowcur,
    uint2* __restrict__ epack, int nnz)
{
    for (int i = blockIdx.x * 256 + threadIdx.x; i < nnz; i += gridDim.x * 256) {
        const int r = rows[i];
        const int pos = atomicAdd(&rowcur[r], 1);
        epack[pos] = make_uint2((unsigned)cols[i], __float_as_uint(vals[i]));
    }
}

// ---------------------------------------------------------------------------
// Kernel 3: per-row gather-accumulate + fused BN-stats accumulation.
// One 64-lane wave per row (2 channels/lane). Writes Zc exactly once.
// stats[0..127]=sum, stats[128..255]=sumsq (pre-zeroed).
// ---------------------------------------------------------------------------
__global__ __launch_bounds__(256) void gather_kernel(
    const float* __restrict__ Zt, const uint2* __restrict__ epack,
    const int* __restrict__ rowptr, float* __restrict__ Zc,
    float* __restrict__ stats, int N)
{
    __shared__ float sbuf[256];
    sbuf[threadIdx.x] = 0.f;
    __syncthreads();

    const int wid  = threadIdx.x >> 6;
    const int lane = threadIdx.x & 63;
    const int c0   = lane * 2;

    float s0 = 0.f, s1 = 0.f, ss0 = 0.f, ss1 = 0.f;

    for (int row = blockIdx.x * 4 + wid; row < N; row += gridDim.x * 4) {
        const int beg = rowptr[row];
        const int end = rowptr[row + 1];

        float a0 = 0.f, a1 = 0.f;
        for (int i = beg; i < end; ++i) {
            const uint2 p = epack[i];                     // wave-uniform 8B load
            const float v = __uint_as_float(p.y);
            const float2 g = *((const float2*)(Zt + (size_t)p.x * COUT + c0));
            a0 = fmaf(v, g.x, a0);
            a1 = fmaf(v, g.y, a1);
        }

        *((float2*)(Zc + (size_t)row * COUT + c0)) = make_float2(a0, a1);
        s0 += a0; s1 += a1;
        ss0 = fmaf(a0, a0, ss0);
        ss1 = fmaf(a1, a1, ss1);
    }

    // combine the block's 4 waves in LDS, then 256 global atomics per block
    atomicAdd(&sbuf[c0], s0);
    atomicAdd(&sbuf[c0 + 1], s1);
    atomicAdd(&sbuf[128 + c0], ss0);
    atomicAdd(&sbuf[128 + c0 + 1], ss1);
    __syncthreads();
    atomicAdd(&stats[threadIdx.x], sbuf[threadIdx.x]);
}

// ---------------------------------------------------------------------------
// Kernel 4: BN(normalize) + ReLU + row-max -> out[N]
// ---------------------------------------------------------------------------
__global__ __launch_bounds__(256) void finalize_kernel(
    const float* __restrict__ Zc, const float* __restrict__ stats,
    const float* __restrict__ gamma, const float* __restrict__ beta,
    float* __restrict__ out, int N)
{
    const int row = blockIdx.x * 4 + (threadIdx.x >> 6);
    if (row >= N) return;
    const int lane = threadIdx.x & 63;
    const int c0 = lane * 2;

    const float2 x = *((const float2*)(Zc + (size_t)row * COUT + c0));

    const float invN = 1.0f / (float)N;
    const float m0 = stats[c0] * invN;
    const float m1 = stats[c0 + 1] * invN;
    const float v0 = stats[128 + c0] * invN - m0 * m0;
    const float v1 = stats[128 + c0 + 1] * invN - m1 * m1;
    const float sc0 = gamma[c0]     * rsqrtf(v0 + BN_EPS);
    const float sc1 = gamma[c0 + 1] * rsqrtf(v1 + BN_EPS);

    float y0 = (x.x - m0) * sc0 + beta[c0];
    float y1 = (x.y - m1) * sc1 + beta[c0 + 1];
    y0 = fmaxf(y0, 0.f);
    y1 = fmaxf(y1, 0.f);

    float mx = fmaxf(y0, y1);
#pragma unroll
    for (int off = 32; off > 0; off >>= 1)
        mx = fmaxf(mx, __shfl_xor(mx, off));

    if (lane == 0) out[row] = mx;
}

// ---------------------------------------------------------------------------
extern "C" void kernel_launch(void* const* d_in, const int* in_sizes, int n_in,
                              void* d_out, int out_size, void* d_ws, size_t ws_size,
                              hipStream_t stream)
{
    const float* Z_H   = (const float*)d_in[0];
    const float* vals  = (const float*)d_in[1];
    const float* W     = (const float*)d_in[2];
    const float* b     = (const float*)d_in[3];
    const float* gamma = (const float*)d_in[4];
    const float* beta  = (const float*)d_in[5];
    const int*   rows  = (const int*)d_in[6];
    const int*   cols  = (const int*)d_in[7];
    float* out = (float*)d_out;

    const int N   = in_sizes[0] / CIN;
    const int nnz = in_sizes[1];

    // workspace layout
    char* ws = (char*)d_ws;
    size_t off = 0;
    float* Zt    = (float*)(ws + off); off += (size_t)N * COUT * sizeof(float);
    float* Zc    = (float*)(ws + off); off += (size_t)N * COUT * sizeof(float);
    uint2* epack = (uint2*)(ws + off); off += (size_t)nnz * sizeof(uint2);
    int*  rowptr = (int*)(ws + off);   off += (size_t)(N + 1) * sizeof(int);
    int*  rowcur = (int*)(ws + off);   off += (size_t)N * sizeof(int);
    int*  rowcnt = (int*)(ws + off);   off += (size_t)N * sizeof(int);
    float* stats = (float*)(ws + off); off += 256 * sizeof(float);

    hipMemsetAsync(rowcnt, 0, (size_t)N * sizeof(int), stream);
    hipMemsetAsync(stats, 0, 256 * sizeof(float), stream);

    // 1) GEMM
    gemm_kernel<<<512, 256, 0, stream>>>(Z_H, W, b, Zt, N);

    // 2) CSR build: histogram -> scan -> scatter
    hist_kernel<<<4096, 256, 0, stream>>>(rows, rowcnt, nnz);
    scan_kernel<<<1, 1024, 0, stream>>>(rowcnt, rowptr, rowcur, N);
    scatter_kernel<<<4096, 256, 0, stream>>>(rows, cols, vals, rowcur, epack, nnz);

    // 3) per-row gather + fused BN stats
    gather_kernel<<<2048, 256, 0, stream>>>(Zt, epack, rowptr, Zc, stats, N);

    // 4) BN + ReLU + rowmax
    finalize_kernel<<<(N + 3) / 4, 256, 0, stream>>>(Zc, stats, gamma, beta, out, N);
}

// Round 3
// 869.738 us; speedup vs baseline: 6.2844x; 1.1682x over previous
//
#include <hip/hip_runtime.h>
#include <hip/hip_bf16.h>

#define CIN  128
#define COUT 128
#define BN_EPS 1e-5f

// round-to-nearest-even f32 -> bf16 bits
__device__ __forceinline__ unsigned short f2bf(float f) {
    unsigned u = __float_as_uint(f);
    u += 0x7fffu + ((u >> 16) & 1u);
    return (unsigned short)(u >> 16);
}

// ---------------------------------------------------------------------------
// Kernel 1: Z_theta[N,128] = Z_H[N,128] @ W[128,128] + b   (output bf16)
// W staged in LDS (64 KB), 32-row Z tiles staged in LDS (16 KB).
// ---------------------------------------------------------------------------
__global__ __launch_bounds__(256) void gemm_kernel(
    const float* __restrict__ Z, const float* __restrict__ W,
    const float* __restrict__ b, unsigned short* __restrict__ Zt, int N)
{
    __shared__ float Wlds[CIN * COUT];      // 64 KB
    __shared__ float zl[32][CIN];           // 16 KB

    const int t = threadIdx.x;

    for (int i = t; i < (CIN * COUT) / 4; i += 256) {
        ((float4*)Wlds)[i] = ((const float4*)W)[i];
    }

    const int c4 = (t & 31) * 4;
    const int rg = t >> 5;
    const float4 bias = *((const float4*)(b + c4));

    const int ntiles = (N + 31) / 32;
    for (int tile = blockIdx.x; tile < ntiles; tile += gridDim.x) {
        const int row0 = tile * 32;
        __syncthreads();
        for (int i = t; i < 1024; i += 256) {
            const int r  = i >> 5;
            const int cc = i & 31;
            const int gr = row0 + r;
            float4 v = make_float4(0.f, 0.f, 0.f, 0.f);
            if (gr < N) v = ((const float4*)(Z + (size_t)gr * CIN))[cc];
            ((float4*)&zl[r][0])[cc] = v;
        }
        __syncthreads();

        float4 acc[4];
#pragma unroll
        for (int r = 0; r < 4; ++r) acc[r] = bias;

        for (int k = 0; k < CIN; ++k) {
            const float4 w = *((const float4*)&Wlds[k * COUT + c4]);
#pragma unroll
            for (int r = 0; r < 4; ++r) {
                const float z = zl[rg * 4 + r][k];
                acc[r].x += z * w.x;
                acc[r].y += z * w.y;
                acc[r].z += z * w.z;
                acc[r].w += z * w.w;
            }
        }

#pragma unroll
        for (int r = 0; r < 4; ++r) {
            const int gr = row0 + rg * 4 + r;
            if (gr < N) {
                ushort4 o;
                o.x = f2bf(acc[r].x);
                o.y = f2bf(acc[r].y);
                o.z = f2bf(acc[r].z);
                o.w = f2bf(acc[r].w);
                *((ushort4*)(Zt + (size_t)gr * COUT + c4)) = o;
            }
        }
    }
}

// ---------------------------------------------------------------------------
// Kernel 2a: histogram of row ids (int4 vectorized reads)
// ---------------------------------------------------------------------------
__global__ __launch_bounds__(256) void hist_kernel(
    const int* __restrict__ rows, int* __restrict__ cnt, int nnz)
{
    const int nnz4 = nnz >> 2;
    const int4* r4 = (const int4*)rows;
    for (int i = blockIdx.x * 256 + threadIdx.x; i < nnz4; i += gridDim.x * 256) {
        const int4 v = r4[i];
        atomicAdd(&cnt[v.x], 1);
        atomicAdd(&cnt[v.y], 1);
        atomicAdd(&cnt[v.z], 1);
        atomicAdd(&cnt[v.w], 1);
    }
    // tail
    const int gid = blockIdx.x * 256 + threadIdx.x;
    const int tail0 = nnz4 << 2;
    if (gid < nnz - tail0) atomicAdd(&cnt[rows[tail0 + gid]], 1);
}

// ---------------------------------------------------------------------------
// Kernel 2b: single-block exclusive scan -> rowptr[N+1], rowcur[N]
// ---------------------------------------------------------------------------
__global__ __launch_bounds__(1024) void scan_kernel(
    const int* __restrict__ cnt, int* __restrict__ rowptr,
    int* __restrict__ rowcur, int N)
{
    const int t = threadIdx.x;
    const int chunk = (N + 1023) / 1024;
    const int begin = t * chunk;
    const int end   = min(begin + chunk, N);

    int s = 0;
    for (int i = begin; i < end; ++i) s += cnt[i];

    __shared__ int sums[1024];
    sums[t] = s;
    __syncthreads();

    for (int off = 1; off < 1024; off <<= 1) {
        int v = (t >= off) ? sums[t - off] : 0;
        __syncthreads();
        sums[t] += v;
        __syncthreads();
    }

    int run = (t == 0) ? 0 : sums[t - 1];
    for (int i = begin; i < end; ++i) {
        rowptr[i] = run;
        rowcur[i] = run;
        run += cnt[i];
    }
    if (t == 0) rowptr[N] = sums[1023];
}

// ---------------------------------------------------------------------------
// Kernel 2c: counting-sort scatter (vectorized reads, packed 8B writes)
// ---------------------------------------------------------------------------
__global__ __launch_bounds__(256) void scatter_kernel(
    const int* __restrict__ rows, const int* __restrict__ cols,
    const float* __restrict__ vals, int* __restrict__ rowcur,
    uint2* __restrict__ epack, int nnz)
{
    const int nnz4 = nnz >> 2;
    const int4*   r4 = (const int4*)rows;
    const int4*   c4 = (const int4*)cols;
    const float4* v4 = (const float4*)vals;

    for (int i = blockIdx.x * 256 + threadIdx.x; i < nnz4; i += gridDim.x * 256) {
        const int4   r = r4[i];
        const int4   c = c4[i];
        const float4 v = v4[i];
        int p;
        p = atomicAdd(&rowcur[r.x], 1); epack[p] = make_uint2((unsigned)c.x, __float_as_uint(v.x));
        p = atomicAdd(&rowcur[r.y], 1); epack[p] = make_uint2((unsigned)c.y, __float_as_uint(v.y));
        p = atomicAdd(&rowcur[r.z], 1); epack[p] = make_uint2((unsigned)c.z, __float_as_uint(v.z));
        p = atomicAdd(&rowcur[r.w], 1); epack[p] = make_uint2((unsigned)c.w, __float_as_uint(v.w));
    }
    // tail
    const int gid = blockIdx.x * 256 + threadIdx.x;
    const int tail0 = nnz4 << 2;
    if (gid < nnz - tail0) {
        const int e = tail0 + gid;
        const int p = atomicAdd(&rowcur[rows[e]], 1);
        epack[p] = make_uint2((unsigned)cols[e], __float_as_uint(vals[e]));
    }
}

// ---------------------------------------------------------------------------
// Kernel 3: per-row gather-accumulate (bf16 Zt) + fused BN stats.
// One 64-lane wave per row, 2 channels/lane (one 4B bf16x2 load per edge).
// 4x unrolled edge loop -> 4 gathers in flight.
// ---------------------------------------------------------------------------
__global__ __launch_bounds__(256) void gather_kernel(
    const unsigned short* __restrict__ Zt, const uint2* __restrict__ epack,
    const int* __restrict__ rowptr, unsigned int* __restrict__ Zc,
    float* __restrict__ stats, int N)
{
    __shared__ float sbuf[256];
    sbuf[threadIdx.x] = 0.f;
    __syncthreads();

    const int wid  = threadIdx.x >> 6;
    const int lane = threadIdx.x & 63;
    const int c0   = lane * 2;

    float s0 = 0.f, s1 = 0.f, ss0 = 0.f, ss1 = 0.f;

    for (int row = blockIdx.x * 4 + wid; row < N; row += gridDim.x * 4) {
        const int beg = rowptr[row];
        const int end = rowptr[row + 1];

        float a0 = 0.f, a1 = 0.f;
        int i = beg;
        const int nb = beg + ((end - beg) & ~3);
        for (; i < nb; i += 4) {
            const uint2 p0 = epack[i];
            const uint2 p1 = epack[i + 1];
            const uint2 p2 = epack[i + 2];
            const uint2 p3 = epack[i + 3];
            const unsigned g0 = *((const unsigned*)(Zt + (size_t)p0.x * COUT) + lane);
            const unsigned g1 = *((const unsigned*)(Zt + (size_t)p1.x * COUT) + lane);
            const unsigned g2 = *((const unsigned*)(Zt + (size_t)p2.x * COUT) + lane);
            const unsigned g3 = *((const unsigned*)(Zt + (size_t)p3.x * COUT) + lane);
            const float v0 = __uint_as_float(p0.y);
            const float v1 = __uint_as_float(p1.y);
            const float v2 = __uint_as_float(p2.y);
            const float v3 = __uint_as_float(p3.y);
            a0 = fmaf(v0, __uint_as_float(g0 << 16), a0);
            a1 = fmaf(v0, __uint_as_float(g0 & 0xffff0000u), a1);
            a0 = fmaf(v1, __uint_as_float(g1 << 16), a0);
            a1 = fmaf(v1, __uint_as_float(g1 & 0xffff0000u), a1);
            a0 = fmaf(v2, __uint_as_float(g2 << 16), a0);
            a1 = fmaf(v2, __uint_as_float(g2 & 0xffff0000u), a1);
            a0 = fmaf(v3, __uint_as_float(g3 << 16), a0);
            a1 = fmaf(v3, __uint_as_float(g3 & 0xffff0000u), a1);
        }
        for (; i < end; ++i) {
            const uint2 p = epack[i];
            const unsigned g = *((const unsigned*)(Zt + (size_t)p.x * COUT) + lane);
            const float v = __uint_as_float(p.y);
            a0 = fmaf(v, __uint_as_float(g << 16), a0);
            a1 = fmaf(v, __uint_as_float(g & 0xffff0000u), a1);
        }

        // store Zc as packed bf16x2
        Zc[(size_t)row * (COUT / 2) + lane] =
            (unsigned)f2bf(a0) | ((unsigned)f2bf(a1) << 16);

        s0 += a0; s1 += a1;
        ss0 = fmaf(a0, a0, ss0);
        ss1 = fmaf(a1, a1, ss1);
    }

    atomicAdd(&sbuf[c0], s0);
    atomicAdd(&sbuf[c0 + 1], s1);
    atomicAdd(&sbuf[128 + c0], ss0);
    atomicAdd(&sbuf[128 + c0 + 1], ss1);
    __syncthreads();
    atomicAdd(&stats[threadIdx.x], sbuf[threadIdx.x]);
}

// ---------------------------------------------------------------------------
// Kernel 4: BN(normalize) + ReLU + row-max -> out[N]  (bf16 Zc input)
// ---------------------------------------------------------------------------
__global__ __launch_bounds__(256) void finalize_kernel(
    const unsigned int* __restrict__ Zc, const float* __restrict__ stats,
    const float* __restrict__ gamma, const float* __restrict__ beta,
    float* __restrict__ out, int N)
{
    const int row = blockIdx.x * 4 + (threadIdx.x >> 6);
    if (row >= N) return;
    const int lane = threadIdx.x & 63;
    const int c0 = lane * 2;

    const unsigned g = Zc[(size_t)row * (COUT / 2) + lane];
    const float x0 = __uint_as_float(g << 16);
    const float x1 = __uint_as_float(g & 0xffff0000u);

    const float invN = 1.0f / (float)N;
    const float m0 = stats[c0] * invN;
    const float m1 = stats[c0 + 1] * invN;
    const float v0 = stats[128 + c0] * invN - m0 * m0;
    const float v1 = stats[128 + c0 + 1] * invN - m1 * m1;
    const float sc0 = gamma[c0]     * rsqrtf(v0 + BN_EPS);
    const float sc1 = gamma[c0 + 1] * rsqrtf(v1 + BN_EPS);

    float y0 = (x0 - m0) * sc0 + beta[c0];
    float y1 = (x1 - m1) * sc1 + beta[c0 + 1];
    y0 = fmaxf(y0, 0.f);
    y1 = fmaxf(y1, 0.f);

    float mx = fmaxf(y0, y1);
#pragma unroll
    for (int off = 32; off > 0; off >>= 1)
        mx = fmaxf(mx, __shfl_xor(mx, off));

    if (lane == 0) out[row] = mx;
}

// ---------------------------------------------------------------------------
extern "C" void kernel_launch(void* const* d_in, const int* in_sizes, int n_in,
                              void* d_out, int out_size, void* d_ws, size_t ws_size,
                              hipStream_t stream)
{
    const float* Z_H   = (const float*)d_in[0];
    const float* vals  = (const float*)d_in[1];
    const float* W     = (const float*)d_in[2];
    const float* b     = (const float*)d_in[3];
    const float* gamma = (const float*)d_in[4];
    const float* beta  = (const float*)d_in[5];
    const int*   rows  = (const int*)d_in[6];
    const int*   cols  = (const int*)d_in[7];
    float* out = (float*)d_out;

    const int N   = in_sizes[0] / CIN;
    const int nnz = in_sizes[1];

    // workspace layout
    char* ws = (char*)d_ws;
    size_t off = 0;
    unsigned short* Zt = (unsigned short*)(ws + off); off += (size_t)N * COUT * sizeof(unsigned short);
    unsigned int*   Zc = (unsigned int*)(ws + off);   off += (size_t)N * (COUT / 2) * sizeof(unsigned int);
    uint2* epack = (uint2*)(ws + off); off += (size_t)nnz * sizeof(uint2);
    int*  rowptr = (int*)(ws + off);   off += (size_t)(N + 1) * sizeof(int);
    int*  rowcur = (int*)(ws + off);   off += (size_t)N * sizeof(int);
    int*  rowcnt = (int*)(ws + off);   off += (size_t)N * sizeof(int);
    float* stats = (float*)(ws + off); off += 256 * sizeof(float);

    hipMemsetAsync(rowcnt, 0, (size_t)N * sizeof(int), stream);
    hipMemsetAsync(stats, 0, 256 * sizeof(float), stream);

    // 1) GEMM (bf16 output)
    gemm_kernel<<<512, 256, 0, stream>>>(Z_H, W, b, Zt, N);

    // 2) CSR build
    {
        const int blocks = min(3200, (nnz / 4 + 255) / 256);
        hist_kernel<<<blocks, 256, 0, stream>>>(rows, rowcnt, nnz);
        scan_kernel<<<1, 1024, 0, stream>>>(rowcnt, rowptr, rowcur, N);
        scatter_kernel<<<blocks, 256, 0, stream>>>(rows, cols, vals, rowcur, epack, nnz);
    }

    // 3) per-row gather + fused BN stats
    gather_kernel<<<2048, 256, 0, stream>>>(Zt, epack, rowptr, Zc, stats, N);

    // 4) BN + ReLU + rowmax
    finalize_kernel<<<(N + 3) / 4, 256, 0, stream>>>(Zc, stats, gamma, beta, out, N);
}

// Round 4
// 639.538 us; speedup vs baseline: 8.5465x; 1.3599x over previous
//
#include <hip/hip_runtime.h>
#include <hip/hip_bf16.h>

#define CIN  128
#define COUT 128
#define BN_EPS 1e-5f
#define RPB   256          // rows per bucket (power of 2)
#define MAXNB 512          // max buckets supported (N <= 131072)

// round-to-nearest-even f32 -> bf16 bits
__device__ __forceinline__ unsigned short f2bf(float f) {
    unsigned u = __float_as_uint(f);
    u += 0x7fffu + ((u >> 16) & 1u);
    return (unsigned short)(u >> 16);
}

// ---------------------------------------------------------------------------
// Kernel 1: Z_theta[N,128] = Z_H[N,128] @ W[128,128] + b   (output bf16)
// ---------------------------------------------------------------------------
__global__ __launch_bounds__(256) void gemm_kernel(
    const float* __restrict__ Z, const float* __restrict__ W,
    const float* __restrict__ b, unsigned short* __restrict__ Zt, int N)
{
    __shared__ float Wlds[CIN * COUT];      // 64 KB
    __shared__ float zl[32][CIN];           // 16 KB

    const int t = threadIdx.x;

    for (int i = t; i < (CIN * COUT) / 4; i += 256) {
        ((float4*)Wlds)[i] = ((const float4*)W)[i];
    }

    const int c4 = (t & 31) * 4;
    const int rg = t >> 5;
    const float4 bias = *((const float4*)(b + c4));

    const int ntiles = (N + 31) / 32;
    for (int tile = blockIdx.x; tile < ntiles; tile += gridDim.x) {
        const int row0 = tile * 32;
        __syncthreads();
        for (int i = t; i < 1024; i += 256) {
            const int r  = i >> 5;
            const int cc = i & 31;
            const int gr = row0 + r;
            float4 v = make_float4(0.f, 0.f, 0.f, 0.f);
            if (gr < N) v = ((const float4*)(Z + (size_t)gr * CIN))[cc];
            ((float4*)&zl[r][0])[cc] = v;
        }
        __syncthreads();

        float4 acc[4];
#pragma unroll
        for (int r = 0; r < 4; ++r) acc[r] = bias;

        for (int k = 0; k < CIN; ++k) {
            const float4 w = *((const float4*)&Wlds[k * COUT + c4]);
#pragma unroll
            for (int r = 0; r < 4; ++r) {
                const float z = zl[rg * 4 + r][k];
                acc[r].x += z * w.x;
                acc[r].y += z * w.y;
                acc[r].z += z * w.z;
                acc[r].w += z * w.w;
            }
        }

#pragma unroll
        for (int r = 0; r < 4; ++r) {
            const int gr = row0 + rg * 4 + r;
            if (gr < N) {
                ushort4 o;
                o.x = f2bf(acc[r].x);
                o.y = f2bf(acc[r].y);
                o.z = f2bf(acc[r].z);
                o.w = f2bf(acc[r].w);
                *((ushort4*)(Zt + (size_t)gr * COUT + c4)) = o;
            }
        }
    }
}

// ---------------------------------------------------------------------------
// Kernel 2a: histogram of row ids (int4 vectorized reads)
// ---------------------------------------------------------------------------
__global__ __launch_bounds__(256) void hist_kernel(
    const int* __restrict__ rows, int* __restrict__ cnt, int nnz)
{
    const int nnz4 = nnz >> 2;
    const int4* r4 = (const int4*)rows;
    for (int i = blockIdx.x * 256 + threadIdx.x; i < nnz4; i += gridDim.x * 256) {
        const int4 v = r4[i];
        atomicAdd(&cnt[v.x], 1);
        atomicAdd(&cnt[v.y], 1);
        atomicAdd(&cnt[v.z], 1);
        atomicAdd(&cnt[v.w], 1);
    }
    const int gid = blockIdx.x * 256 + threadIdx.x;
    const int tail0 = nnz4 << 2;
    if (gid < nnz - tail0) atomicAdd(&cnt[rows[tail0 + gid]], 1);
}

// ---------------------------------------------------------------------------
// Kernel 2b: single-block exclusive scan -> rowptr[N+1] + bucket bases
// ---------------------------------------------------------------------------
__global__ __launch_bounds__(1024) void scan_kernel(
    const int* __restrict__ cnt, int* __restrict__ rowptr,
    int* __restrict__ bucketCur, int N)
{
    const int t = threadIdx.x;
    const int chunk = (N + 1023) / 1024;
    const int begin = t * chunk;
    const int end   = min(begin + chunk, N);

    int s = 0;
    for (int i = begin; i < end; ++i) s += cnt[i];

    __shared__ int sums[1024];
    sums[t] = s;
    __syncthreads();

    for (int off = 1; off < 1024; off <<= 1) {
        int v = (t >= off) ? sums[t - off] : 0;
        __syncthreads();
        sums[t] += v;
        __syncthreads();
    }

    int run = (t == 0) ? 0 : sums[t - 1];
    for (int i = begin; i < end; ++i) {
        rowptr[i] = run;
        if ((i & (RPB - 1)) == 0) bucketCur[i / RPB] = run;
        run += cnt[i];
    }
    if (t == 0) rowptr[N] = sums[1023];
}

// ---------------------------------------------------------------------------
// Kernel 2c: bucket partition. Each block takes 4096 edges, LDS-histograms
// them over coarse buckets (RPB rows each), bulk-reserves contiguous space
// per bucket, writes grouped runs -> ebuck. Payload: col | rowlocal<<17, val.
// ---------------------------------------------------------------------------
__global__ __launch_bounds__(256) void partition_kernel(
    const int* __restrict__ rows, const int* __restrict__ cols,
    const float* __restrict__ vals, int* __restrict__ bucketCur,
    uint2* __restrict__ ebuck, int nnz, int NB)
{
    __shared__ int hist[MAXNB];
    __shared__ int basecur[MAXNB];
    const int t = threadIdx.x;

    for (int i = t; i < NB; i += 256) hist[i] = 0;
    __syncthreads();

    const int chunk0 = blockIdx.x * 4096;
    const int cend   = min(chunk0 + 4096, nnz);

    int rloc[16];
#pragma unroll
    for (int j = 0; j < 16; ++j) {
        const int i = chunk0 + j * 256 + t;
        int r = -1;
        if (i < cend) r = rows[i];
        rloc[j] = r;
        if (r >= 0) atomicAdd(&hist[r / RPB], 1);
    }
    __syncthreads();

    for (int i = t; i < NB; i += 256) {
        const int c = hist[i];
        basecur[i] = (c > 0) ? atomicAdd(&bucketCur[i], c) : 0;
    }
    __syncthreads();

#pragma unroll
    for (int j = 0; j < 16; ++j) {
        const int i = chunk0 + j * 256 + t;
        const int r = rloc[j];
        if (r >= 0) {
            const int p = atomicAdd(&basecur[r / RPB], 1);
            ebuck[p] = make_uint2((unsigned)cols[i] | ((unsigned)(r & (RPB - 1)) << 17),
                                  __float_as_uint(vals[i]));
        }
    }
}

// ---------------------------------------------------------------------------
// Kernel 2d: within-bucket exact CSR sort. One block per bucket; the block
// owns a contiguous epack region, so every written cache line is
// single-owner (write amplification ~1).
// ---------------------------------------------------------------------------
__global__ __launch_bounds__(1024) void bucket_sort_kernel(
    const uint2* __restrict__ ebuck, const int* __restrict__ rowptr,
    uint2* __restrict__ epack, int N)
{
    __shared__ int cur[RPB];
    const int b  = blockIdx.x;
    const int r0 = b * RPB;
    const int nrows = min(RPB, N - r0);
    const int t = threadIdx.x;

    if (t < nrows) cur[t] = rowptr[r0 + t];
    __syncthreads();

    const int ebeg = rowptr[r0];
    const int eend = rowptr[r0 + nrows];

    for (int i = ebeg + t; i < eend; i += 1024) {
        const uint2 e = ebuck[i];
        const int rl  = (int)(e.x >> 17);
        const int pos = atomicAdd(&cur[rl], 1);
        epack[pos] = make_uint2(e.x & 0x1FFFFu, e.y);
    }
}

// ---------------------------------------------------------------------------
// Kernel 3: per-row gather-accumulate (bf16 Zt) + fused BN stats.
// ---------------------------------------------------------------------------
__global__ __launch_bounds__(256) void gather_kernel(
    const unsigned short* __restrict__ Zt, const uint2* __restrict__ epack,
    const int* __restrict__ rowptr, unsigned int* __restrict__ Zc,
    float* __restrict__ stats, int N)
{
    __shared__ float sbuf[256];
    sbuf[threadIdx.x] = 0.f;
    __syncthreads();

    const int wid  = threadIdx.x >> 6;
    const int lane = threadIdx.x & 63;
    const int c0   = lane * 2;

    float s0 = 0.f, s1 = 0.f, ss0 = 0.f, ss1 = 0.f;

    for (int row = blockIdx.x * 4 + wid; row < N; row += gridDim.x * 4) {
        const int beg = rowptr[row];
        const int end = rowptr[row + 1];

        float a0 = 0.f, a1 = 0.f;
        int i = beg;
        const int nb = beg + ((end - beg) & ~3);
        for (; i < nb; i += 4) {
            const uint2 p0 = epack[i];
            const uint2 p1 = epack[i + 1];
            const uint2 p2 = epack[i + 2];
            const uint2 p3 = epack[i + 3];
            const unsigned g0 = *((const unsigned*)(Zt + (size_t)p0.x * COUT) + lane);
            const unsigned g1 = *((const unsigned*)(Zt + (size_t)p1.x * COUT) + lane);
            const unsigned g2 = *((const unsigned*)(Zt + (size_t)p2.x * COUT) + lane);
            const unsigned g3 = *((const unsigned*)(Zt + (size_t)p3.x * COUT) + lane);
            const float v0 = __uint_as_float(p0.y);
            const float v1 = __uint_as_float(p1.y);
            const float v2 = __uint_as_float(p2.y);
            const float v3 = __uint_as_float(p3.y);
            a0 = fmaf(v0, __uint_as_float(g0 << 16), a0);
            a1 = fmaf(v0, __uint_as_float(g0 & 0xffff0000u), a1);
            a0 = fmaf(v1, __uint_as_float(g1 << 16), a0);
            a1 = fmaf(v1, __uint_as_float(g1 & 0xffff0000u), a1);
            a0 = fmaf(v2, __uint_as_float(g2 << 16), a0);
            a1 = fmaf(v2, __uint_as_float(g2 & 0xffff0000u), a1);
            a0 = fmaf(v3, __uint_as_float(g3 << 16), a0);
            a1 = fmaf(v3, __uint_as_float(g3 & 0xffff0000u), a1);
        }
        for (; i < end; ++i) {
            const uint2 p = epack[i];
            const unsigned g = *((const unsigned*)(Zt + (size_t)p.x * COUT) + lane);
            const float v = __uint_as_float(p.y);
            a0 = fmaf(v, __uint_as_float(g << 16), a0);
            a1 = fmaf(v, __uint_as_float(g & 0xffff0000u), a1);
        }

        Zc[(size_t)row * (COUT / 2) + lane] =
            (unsigned)f2bf(a0) | ((unsigned)f2bf(a1) << 16);

        s0 += a0; s1 += a1;
        ss0 = fmaf(a0, a0, ss0);
        ss1 = fmaf(a1, a1, ss1);
    }

    atomicAdd(&sbuf[c0], s0);
    atomicAdd(&sbuf[c0 + 1], s1);
    atomicAdd(&sbuf[128 + c0], ss0);
    atomicAdd(&sbuf[128 + c0 + 1], ss1);
    __syncthreads();
    atomicAdd(&stats[threadIdx.x], sbuf[threadIdx.x]);
}

// ---------------------------------------------------------------------------
// Kernel 4: BN(normalize) + ReLU + row-max -> out[N]  (bf16 Zc input)
// ---------------------------------------------------------------------------
__global__ __launch_bounds__(256) void finalize_kernel(
    const unsigned int* __restrict__ Zc, const float* __restrict__ stats,
    const float* __restrict__ gamma, const float* __restrict__ beta,
    float* __restrict__ out, int N)
{
    const int row = blockIdx.x * 4 + (threadIdx.x >> 6);
    if (row >= N) return;
    const int lane = threadIdx.x & 63;
    const int c0 = lane * 2;

    const unsigned g = Zc[(size_t)row * (COUT / 2) + lane];
    const float x0 = __uint_as_float(g << 16);
    const float x1 = __uint_as_float(g & 0xffff0000u);

    const float invN = 1.0f / (float)N;
    const float m0 = stats[c0] * invN;
    const float m1 = stats[c0 + 1] * invN;
    const float v0 = stats[128 + c0] * invN - m0 * m0;
    const float v1 = stats[128 + c0 + 1] * invN - m1 * m1;
    const float sc0 = gamma[c0]     * rsqrtf(v0 + BN_EPS);
    const float sc1 = gamma[c0 + 1] * rsqrtf(v1 + BN_EPS);

    float y0 = (x0 - m0) * sc0 + beta[c0];
    float y1 = (x1 - m1) * sc1 + beta[c0 + 1];
    y0 = fmaxf(y0, 0.f);
    y1 = fmaxf(y1, 0.f);

    float mx = fmaxf(y0, y1);
#pragma unroll
    for (int off = 32; off > 0; off >>= 1)
        mx = fmaxf(mx, __shfl_xor(mx, off));

    if (lane == 0) out[row] = mx;
}

// ---------------------------------------------------------------------------
extern "C" void kernel_launch(void* const* d_in, const int* in_sizes, int n_in,
                              void* d_out, int out_size, void* d_ws, size_t ws_size,
                              hipStream_t stream)
{
    const float* Z_H   = (const float*)d_in[0];
    const float* vals  = (const float*)d_in[1];
    const float* W     = (const float*)d_in[2];
    const float* b     = (const float*)d_in[3];
    const float* gamma = (const float*)d_in[4];
    const float* beta  = (const float*)d_in[5];
    const int*   rows  = (const int*)d_in[6];
    const int*   cols  = (const int*)d_in[7];
    float* out = (float*)d_out;

    const int N   = in_sizes[0] / CIN;
    const int nnz = in_sizes[1];
    const int NB  = (N + RPB - 1) / RPB;

    // workspace layout
    char* ws = (char*)d_ws;
    size_t off = 0;
    unsigned short* Zt = (unsigned short*)(ws + off); off += (size_t)N * COUT * sizeof(unsigned short);
    unsigned int*   Zc = (unsigned int*)(ws + off);   off += (size_t)N * (COUT / 2) * sizeof(unsigned int);
    uint2* ebuck = (uint2*)(ws + off); off += (size_t)nnz * sizeof(uint2);
    uint2* epack = (uint2*)(ws + off); off += (size_t)nnz * sizeof(uint2);
    int*  rowptr = (int*)(ws + off);   off += (size_t)(N + 1) * sizeof(int);
    int*  rowcnt = (int*)(ws + off);   off += (size_t)N * sizeof(int);
    int*  bucketCur = (int*)(ws + off); off += (size_t)NB * sizeof(int);
    float* stats = (float*)(ws + off); off += 256 * sizeof(float);

    hipMemsetAsync(rowcnt, 0, (size_t)N * sizeof(int), stream);
    hipMemsetAsync(stats, 0, 256 * sizeof(float), stream);

    // 1) GEMM (bf16 output)
    gemm_kernel<<<512, 256, 0, stream>>>(Z_H, W, b, Zt, N);

    // 2) CSR build: hist -> scan -> bucket partition -> in-bucket sort
    hist_kernel<<<3125, 256, 0, stream>>>(rows, rowcnt, nnz);
    scan_kernel<<<1, 1024, 0, stream>>>(rowcnt, rowptr, bucketCur, N);
    partition_kernel<<<(nnz + 4095) / 4096, 256, 0, stream>>>(
        rows, cols, vals, bucketCur, ebuck, nnz, NB);
    bucket_sort_kernel<<<NB, 1024, 0, stream>>>(ebuck, rowptr, epack, N);

    // 3) per-row gather + fused BN stats
    gather_kernel<<<2048, 256, 0, stream>>>(Zt, epack, rowptr, Zc, stats, N);

    // 4) BN + ReLU + rowmax
    finalize_kernel<<<(N + 3) / 4, 256, 0, stream>>>(Zc, stats, gamma, beta, out, N);
}

// Round 5
// 484.892 us; speedup vs baseline: 11.2722x; 1.3189x over previous
//
#include <hip/hip_runtime.h>
#include <hip/hip_bf16.h>

#define CIN  128
#define COUT 128
#define BN_EPS 1e-5f
#define RPB   256          // rows per bucket (power of 2)
#define MAXNB 512          // max buckets supported (N <= 131072)
#define SCAN_T 16384       // threads in hierarchical scan

// round-to-nearest-even f32 -> bf16 bits
__device__ __forceinline__ unsigned short f2bf(float f) {
    unsigned u = __float_as_uint(f);
    u += 0x7fffu + ((u >> 16) & 1u);
    return (unsigned short)(u >> 16);
}

// ---------------------------------------------------------------------------
// Kernel 1: Z_theta[N,128] = Z_H[N,128] @ W[128,128] + b   (output bf16)
// ---------------------------------------------------------------------------
__global__ __launch_bounds__(256) void gemm_kernel(
    const float* __restrict__ Z, const float* __restrict__ W,
    const float* __restrict__ b, unsigned short* __restrict__ Zt, int N)
{
    __shared__ float Wlds[CIN * COUT];      // 64 KB
    __shared__ float zl[32][CIN];           // 16 KB

    const int t = threadIdx.x;

    for (int i = t; i < (CIN * COUT) / 4; i += 256) {
        ((float4*)Wlds)[i] = ((const float4*)W)[i];
    }

    const int c4 = (t & 31) * 4;
    const int rg = t >> 5;
    const float4 bias = *((const float4*)(b + c4));

    const int ntiles = (N + 31) / 32;
    for (int tile = blockIdx.x; tile < ntiles; tile += gridDim.x) {
        const int row0 = tile * 32;
        __syncthreads();
        for (int i = t; i < 1024; i += 256) {
            const int r  = i >> 5;
            const int cc = i & 31;
            const int gr = row0 + r;
            float4 v = make_float4(0.f, 0.f, 0.f, 0.f);
            if (gr < N) v = ((const float4*)(Z + (size_t)gr * CIN))[cc];
            ((float4*)&zl[r][0])[cc] = v;
        }
        __syncthreads();

        float4 acc[4];
#pragma unroll
        for (int r = 0; r < 4; ++r) acc[r] = bias;

        for (int k = 0; k < CIN; ++k) {
            const float4 w = *((const float4*)&Wlds[k * COUT + c4]);
#pragma unroll
            for (int r = 0; r < 4; ++r) {
                const float z = zl[rg * 4 + r][k];
                acc[r].x += z * w.x;
                acc[r].y += z * w.y;
                acc[r].z += z * w.z;
                acc[r].w += z * w.w;
            }
        }

#pragma unroll
        for (int r = 0; r < 4; ++r) {
            const int gr = row0 + rg * 4 + r;
            if (gr < N) {
                ushort4 o;
                o.x = f2bf(acc[r].x);
                o.y = f2bf(acc[r].y);
                o.z = f2bf(acc[r].z);
                o.w = f2bf(acc[r].w);
                *((ushort4*)(Zt + (size_t)gr * COUT + c4)) = o;
            }
        }
    }
}

// ---------------------------------------------------------------------------
// Kernel 2a: histogram of row ids (int4 vectorized reads)
// ---------------------------------------------------------------------------
__global__ __launch_bounds__(256) void hist_kernel(
    const int* __restrict__ rows, int* __restrict__ cnt, int nnz)
{
    const int nnz4 = nnz >> 2;
    const int4* r4 = (const int4*)rows;
    for (int i = blockIdx.x * 256 + threadIdx.x; i < nnz4; i += gridDim.x * 256) {
        const int4 v = r4[i];
        atomicAdd(&cnt[v.x], 1);
        atomicAdd(&cnt[v.y], 1);
        atomicAdd(&cnt[v.z], 1);
        atomicAdd(&cnt[v.w], 1);
    }
    const int gid = blockIdx.x * 256 + threadIdx.x;
    const int tail0 = nnz4 << 2;
    if (gid < nnz - tail0) atomicAdd(&cnt[rows[tail0 + gid]], 1);
}

// ---------------------------------------------------------------------------
// Kernel 2b-1: per-thread partial sums over row-count chunks
// ---------------------------------------------------------------------------
__global__ __launch_bounds__(256) void scan_part_kernel(
    const int* __restrict__ cnt, int* __restrict__ tsum, int N, int CH)
{
    const int g = blockIdx.x * 256 + threadIdx.x;
    const int b = g * CH;
    const int e = min(b + CH, N);
    int s = 0;
    for (int i = b; i < e; ++i) s += cnt[i];
    tsum[g] = s;
}

// ---------------------------------------------------------------------------
// Kernel 2b-2: scan 16384 partials in one block (16 per thread)
// ---------------------------------------------------------------------------
__global__ __launch_bounds__(1024) void scan_mid_kernel(
    int* __restrict__ tsum, int* __restrict__ rowptrN)
{
    const int t = threadIdx.x;
    int loc[16];
    int s = 0;
#pragma unroll
    for (int j = 0; j < 16; ++j) { loc[j] = tsum[t * 16 + j]; s += loc[j]; }

    __shared__ int sums[1024];
    sums[t] = s;
    __syncthreads();
    for (int off = 1; off < 1024; off <<= 1) {
        int v = (t >= off) ? sums[t - off] : 0;
        __syncthreads();
        sums[t] += v;
        __syncthreads();
    }

    int run = (t == 0) ? 0 : sums[t - 1];
#pragma unroll
    for (int j = 0; j < 16; ++j) { const int c = loc[j]; tsum[t * 16 + j] = run; run += c; }
    if (t == 1023) *rowptrN = run;   // total nnz
}

// ---------------------------------------------------------------------------
// Kernel 2b-3: write rowptr + bucket bases from per-thread bases
// ---------------------------------------------------------------------------
__global__ __launch_bounds__(256) void scan_write_kernel(
    const int* __restrict__ cnt, const int* __restrict__ tsum,
    int* __restrict__ rowptr, int* __restrict__ bucketCur, int N, int CH)
{
    const int g = blockIdx.x * 256 + threadIdx.x;
    const int b = g * CH;
    const int e = min(b + CH, N);
    int run = tsum[g];
    for (int i = b; i < e; ++i) {
        rowptr[i] = run;
        if ((i & (RPB - 1)) == 0) bucketCur[i / RPB] = run;
        run += cnt[i];
    }
}

// ---------------------------------------------------------------------------
// Kernel 2c: bucket partition (4096 edges/block, grouped bucket runs)
// ---------------------------------------------------------------------------
__global__ __launch_bounds__(256) void partition_kernel(
    const int* __restrict__ rows, const int* __restrict__ cols,
    const float* __restrict__ vals, int* __restrict__ bucketCur,
    uint2* __restrict__ ebuck, int nnz, int NB)
{
    __shared__ int hist[MAXNB];
    __shared__ int basecur[MAXNB];
    const int t = threadIdx.x;

    for (int i = t; i < NB; i += 256) hist[i] = 0;
    __syncthreads();

    const int chunk0 = blockIdx.x * 4096;
    const int cend   = min(chunk0 + 4096, nnz);

    int rloc[16];
#pragma unroll
    for (int j = 0; j < 16; ++j) {
        const int i = chunk0 + j * 256 + t;
        int r = -1;
        if (i < cend) r = rows[i];
        rloc[j] = r;
        if (r >= 0) atomicAdd(&hist[r / RPB], 1);
    }
    __syncthreads();

    for (int i = t; i < NB; i += 256) {
        const int c = hist[i];
        basecur[i] = (c > 0) ? atomicAdd(&bucketCur[i], c) : 0;
    }
    __syncthreads();

#pragma unroll
    for (int j = 0; j < 16; ++j) {
        const int i = chunk0 + j * 256 + t;
        const int r = rloc[j];
        if (r >= 0) {
            const int p = atomicAdd(&basecur[r / RPB], 1);
            ebuck[p] = make_uint2((unsigned)cols[i] | ((unsigned)(r & (RPB - 1)) << 17),
                                  __float_as_uint(vals[i]));
        }
    }
}

// ---------------------------------------------------------------------------
// Kernel 2d: within-bucket exact CSR sort (single-owner cache lines)
// ---------------------------------------------------------------------------
__global__ __launch_bounds__(1024) void bucket_sort_kernel(
    const uint2* __restrict__ ebuck, const int* __restrict__ rowptr,
    uint2* __restrict__ epack, int N)
{
    __shared__ int cur[RPB];
    const int b  = blockIdx.x;
    const int r0 = b * RPB;
    const int nrows = min(RPB, N - r0);
    const int t = threadIdx.x;

    if (t < nrows) cur[t] = rowptr[r0 + t];
    __syncthreads();

    const int ebeg = rowptr[r0];
    const int eend = rowptr[r0 + nrows];

    for (int i = ebeg + t; i < eend; i += 1024) {
        const uint2 e = ebuck[i];
        const int rl  = (int)(e.x >> 17);
        const int pos = atomicAdd(&cur[rl], 1);
        epack[pos] = make_uint2(e.x & 0x1FFFFu, e.y);
    }
}

// ---------------------------------------------------------------------------
// Kernel 3: per-row gather-accumulate, 8 B/lane.
// lane = (edge-parity eo, channel-group cg of 4 channels).
// Each wave gathers TWO edges per load instruction; halves combined by one
// shfl_xor(32) per row. Fused BN stats in registers.
// ---------------------------------------------------------------------------
__global__ __launch_bounds__(256) void gather_kernel(
    const unsigned short* __restrict__ Zt, const uint2* __restrict__ epack,
    const int* __restrict__ rowptr, unsigned int* __restrict__ Zc,
    float* __restrict__ stats, int N)
{
    __shared__ float sbuf[256];
    sbuf[threadIdx.x] = 0.f;
    __syncthreads();

    const int wid  = threadIdx.x >> 6;
    const int lane = threadIdx.x & 63;
    const int eo   = lane >> 5;        // edge parity 0/1
    const int cg   = lane & 31;        // channel group: channels cg*4..cg*4+3

    float s0 = 0.f, s1 = 0.f, s2 = 0.f, s3 = 0.f;
    float q0 = 0.f, q1 = 0.f, q2 = 0.f, q3 = 0.f;

    for (int row = blockIdx.x * 4 + wid; row < N; row += gridDim.x * 4) {
        const int beg = rowptr[row];
        const int end = rowptr[row + 1];

        float a0 = 0.f, a1 = 0.f, a2 = 0.f, a3 = 0.f;

        int i = beg + eo;
        // 2 pair-steps per iter -> 4 edges in flight per wave
        for (; i + 2 < end; i += 4) {
            const uint2 p = epack[i];
            const uint2 q = epack[i + 2];
            const uint2 g = *((const uint2*)(Zt + (size_t)p.x * COUT + cg * 4));
            const uint2 h = *((const uint2*)(Zt + (size_t)q.x * COUT + cg * 4));
            const float vp = __uint_as_float(p.y);
            const float vq = __uint_as_float(q.y);
            a0 = fmaf(vp, __uint_as_float(g.x << 16), a0);
            a1 = fmaf(vp, __uint_as_float(g.x & 0xffff0000u), a1);
            a2 = fmaf(vp, __uint_as_float(g.y << 16), a2);
            a3 = fmaf(vp, __uint_as_float(g.y & 0xffff0000u), a3);
            a0 = fmaf(vq, __uint_as_float(h.x << 16), a0);
            a1 = fmaf(vq, __uint_as_float(h.x & 0xffff0000u), a1);
            a2 = fmaf(vq, __uint_as_float(h.y << 16), a2);
            a3 = fmaf(vq, __uint_as_float(h.y & 0xffff0000u), a3);
        }
        for (; i < end; i += 2) {
            const uint2 p = epack[i];
            const uint2 g = *((const uint2*)(Zt + (size_t)p.x * COUT + cg * 4));
            const float vp = __uint_as_float(p.y);
            a0 = fmaf(vp, __uint_as_float(g.x << 16), a0);
            a1 = fmaf(vp, __uint_as_float(g.x & 0xffff0000u), a1);
            a2 = fmaf(vp, __uint_as_float(g.y << 16), a2);
            a3 = fmaf(vp, __uint_as_float(g.y & 0xffff0000u), a3);
        }

        // combine the two edge-parity halves (lane <-> lane+32)
        a0 += __shfl_xor(a0, 32);
        a1 += __shfl_xor(a1, 32);
        a2 += __shfl_xor(a2, 32);
        a3 += __shfl_xor(a3, 32);

        if (eo == 0) {
            uint2 o;
            o.x = (unsigned)f2bf(a0) | ((unsigned)f2bf(a1) << 16);
            o.y = (unsigned)f2bf(a2) | ((unsigned)f2bf(a3) << 16);
            *((uint2*)(Zc + (size_t)row * (COUT / 2) + cg * 2)) = o;
            s0 += a0; s1 += a1; s2 += a2; s3 += a3;
            q0 = fmaf(a0, a0, q0);
            q1 = fmaf(a1, a1, q1);
            q2 = fmaf(a2, a2, q2);
            q3 = fmaf(a3, a3, q3);
        }
    }

    if (eo == 0) {
        const int c0 = cg * 4;
        atomicAdd(&sbuf[c0 + 0], s0);
        atomicAdd(&sbuf[c0 + 1], s1);
        atomicAdd(&sbuf[c0 + 2], s2);
        atomicAdd(&sbuf[c0 + 3], s3);
        atomicAdd(&sbuf[128 + c0 + 0], q0);
        atomicAdd(&sbuf[128 + c0 + 1], q1);
        atomicAdd(&sbuf[128 + c0 + 2], q2);
        atomicAdd(&sbuf[128 + c0 + 3], q3);
    }
    __syncthreads();
    atomicAdd(&stats[threadIdx.x], sbuf[threadIdx.x]);
}

// ---------------------------------------------------------------------------
// Kernel 4: BN(normalize) + ReLU + row-max -> out[N]  (bf16 Zc input)
// ---------------------------------------------------------------------------
__global__ __launch_bounds__(256) void finalize_kernel(
    const unsigned int* __restrict__ Zc, const float* __restrict__ stats,
    const float* __restrict__ gamma, const float* __restrict__ beta,
    float* __restrict__ out, int N)
{
    const int row = blockIdx.x * 4 + (threadIdx.x >> 6);
    if (row >= N) return;
    const int lane = threadIdx.x & 63;
    const int c0 = lane * 2;

    const unsigned g = Zc[(size_t)row * (COUT / 2) + lane];
    const float x0 = __uint_as_float(g << 16);
    const float x1 = __uint_as_float(g & 0xffff0000u);

    const float invN = 1.0f / (float)N;
    const float m0 = stats[c0] * invN;
    const float m1 = stats[c0 + 1] * invN;
    const float v0 = stats[128 + c0] * invN - m0 * m0;
    const float v1 = stats[128 + c0 + 1] * invN - m1 * m1;
    const float sc0 = gamma[c0]     * rsqrtf(v0 + BN_EPS);
    const float sc1 = gamma[c0 + 1] * rsqrtf(v1 + BN_EPS);

    float y0 = (x0 - m0) * sc0 + beta[c0];
    float y1 = (x1 - m1) * sc1 + beta[c0 + 1];
    y0 = fmaxf(y0, 0.f);
    y1 = fmaxf(y1, 0.f);

    float mx = fmaxf(y0, y1);
#pragma unroll
    for (int off = 32; off > 0; off >>= 1)
        mx = fmaxf(mx, __shfl_xor(mx, off));

    if (lane == 0) out[row] = mx;
}

// ---------------------------------------------------------------------------
extern "C" void kernel_launch(void* const* d_in, const int* in_sizes, int n_in,
                              void* d_out, int out_size, void* d_ws, size_t ws_size,
                              hipStream_t stream)
{
    const float* Z_H   = (const float*)d_in[0];
    const float* vals  = (const float*)d_in[1];
    const float* W     = (const float*)d_in[2];
    const float* b     = (const float*)d_in[3];
    const float* gamma = (const float*)d_in[4];
    const float* beta  = (const float*)d_in[5];
    const int*   rows  = (const int*)d_in[6];
    const int*   cols  = (const int*)d_in[7];
    float* out = (float*)d_out;

    const int N   = in_sizes[0] / CIN;
    const int nnz = in_sizes[1];
    const int NB  = (N + RPB - 1) / RPB;
    const int CH  = (N + SCAN_T - 1) / SCAN_T;

    // workspace layout
    char* ws = (char*)d_ws;
    size_t off = 0;
    unsigned short* Zt = (unsigned short*)(ws + off); off += (size_t)N * COUT * sizeof(unsigned short);
    unsigned int*   Zc = (unsigned int*)(ws + off);   off += (size_t)N * (COUT / 2) * sizeof(unsigned int);
    uint2* ebuck = (uint2*)(ws + off); off += (size_t)nnz * sizeof(uint2);
    uint2* epack = (uint2*)(ws + off); off += (size_t)nnz * sizeof(uint2);
    int*  rowptr = (int*)(ws + off);   off += (size_t)(N + 1) * sizeof(int);
    int*  rowcnt = (int*)(ws + off);   off += (size_t)N * sizeof(int);
    int*  tsum   = (int*)(ws + off);   off += (size_t)SCAN_T * sizeof(int);
    int*  bucketCur = (int*)(ws + off); off += (size_t)NB * sizeof(int);
    float* stats = (float*)(ws + off); off += 256 * sizeof(float);

    hipMemsetAsync(rowcnt, 0, (size_t)N * sizeof(int), stream);
    hipMemsetAsync(stats, 0, 256 * sizeof(float), stream);

    // 1) GEMM (bf16 output)
    gemm_kernel<<<512, 256, 0, stream>>>(Z_H, W, b, Zt, N);

    // 2) CSR build: hist -> hierarchical scan -> bucket partition -> sort
    hist_kernel<<<(nnz / 4 + 255) / 256, 256, 0, stream>>>(rows, rowcnt, nnz);
    scan_part_kernel<<<SCAN_T / 256, 256, 0, stream>>>(rowcnt, tsum, N, CH);
    scan_mid_kernel<<<1, 1024, 0, stream>>>(tsum, rowptr + N);
    scan_write_kernel<<<SCAN_T / 256, 256, 0, stream>>>(rowcnt, tsum, rowptr, bucketCur, N, CH);
    partition_kernel<<<(nnz + 4095) / 4096, 256, 0, stream>>>(
        rows, cols, vals, bucketCur, ebuck, nnz, NB);
    bucket_sort_kernel<<<NB, 1024, 0, stream>>>(ebuck, rowptr, epack, N);

    // 3) per-row gather + fused BN stats
    gather_kernel<<<2048, 256, 0, stream>>>(Zt, epack, rowptr, Zc, stats, N);

    // 4) BN + ReLU + rowmax
    finalize_kernel<<<(N + 3) / 4, 256, 0, stream>>>(Zc, stats, gamma, beta, out, N);
}